// Round 1
// baseline (2745.698 us; speedup 1.0000x reference)
//
#include <hip/hip_runtime.h>
#include <stdint.h>
#include <stddef.h>

// ---------------------------------------------------------------------------
// TextRNN: embed -> BiLSTM(512 steps) -> linear -> softmax   (MI355X gfx950)
//
// K0: transpose/cast Wx,Wh (f32 [256][1024]) -> bf16 [1024][256]  (col-major)
// K1: zx[dir][t][col][b] (bf16) = (emb[tokens] @ Wx + b) via mfma 16x16x32 bf16
// K2: 512-step recurrence; 16 wgs/dir each own 16 h-dims (64 gate cols),
//     Wh slice in LDS, h exchanged via global bf16 double buffer + per-step
//     counters with agent-scope release/acquire fences.
// K3: logits = [h_f|h_b] @ W_out + b_out; softmax -> d_out (f32 64x10)
// ---------------------------------------------------------------------------

typedef __attribute__((ext_vector_type(8))) short   short8;
typedef __attribute__((ext_vector_type(4))) float   f32x4;
typedef __attribute__((ext_vector_type(4))) unsigned short ushort4v;

#define S_WG 16   // workgroups per direction in K2

// ws byte offsets
#define ZX_OFF    ((size_t)0)                        // 2*512*1024*64 bf16 = 134217728 B
#define WXT_OFF   ((size_t)134217728)                // 2*1024*256 bf16    = 1048576 B
#define WHT_OFF   ((size_t)135266304)                // 2*1024*256 bf16    = 1048576 B
#define HBUF_OFF  ((size_t)136314880)                // 2 dir * 2 buf * 64*256 bf16 = 131072 B
#define CTR_OFF   ((size_t)136445952)                // 2*512 int = 4096 B
#define WS_NEED   ((size_t)136450048)

__device__ __forceinline__ unsigned short f2bf(float f) {
  unsigned int u = __builtin_bit_cast(unsigned int, f);
  u += 0x7fffu + ((u >> 16) & 1u);            // RNE
  return (unsigned short)(u >> 16);
}
__device__ __forceinline__ float bf2f(unsigned short b) {
  unsigned int u = ((unsigned int)b) << 16;
  return __builtin_bit_cast(float, u);
}
__device__ __forceinline__ float sigf(float x) { return 1.0f / (1.0f + __expf(-x)); }
__device__ __forceinline__ float tanhf_(float x) {
  float t = __expf(-2.0f * fabsf(x));
  float r = (1.0f - t) / (1.0f + t);          // no inf/NaN for any x
  return copysignf(r, x);
}

// ---------------------------------------------------------------------------
// K0: W (f32 [256][1024]) -> Wt (bf16 [1024][256]).  z selects matrix.
__global__ __launch_bounds__(256) void k0_transpose(
    const float* __restrict__ wxf, const float* __restrict__ wxb,
    const float* __restrict__ whf, const float* __restrict__ whb,
    unsigned short* __restrict__ wxt, unsigned short* __restrict__ wht) {
  __shared__ float lds[32][33];
  int mat = blockIdx.z;
  const float* src = (mat == 0) ? wxf : (mat == 1) ? wxb : (mat == 2) ? whf : whb;
  unsigned short* dst = (mat == 0) ? wxt : (mat == 1) ? (wxt + 262144)
                      : (mat == 2) ? wht : (wht + 262144);
  int k0 = blockIdx.x * 32;
  int n0 = blockIdx.y * 32;
  int tx = threadIdx.x & 31, ty = threadIdx.x >> 5;   // ty 0..7
#pragma unroll
  for (int r = 0; r < 4; r++) {
    int k = ty + r * 8;
    lds[k][tx] = src[(size_t)(k0 + k) * 1024 + n0 + tx];
  }
  __syncthreads();
#pragma unroll
  for (int r = 0; r < 4; r++) {
    int n = ty + r * 8;
    dst[(size_t)(n0 + n) * 256 + k0 + tx] = f2bf(lds[tx][n]);
  }
}

// ---------------------------------------------------------------------------
// K1: zx[dir][t][col][b] = emb[tok[b][t_src]] @ Wx + bias   (bf16 out)
// grid (512 t, 16 coltiles, 2 dir), block 256 (4 waves). Tile: 64 b x 64 cols.
__global__ __launch_bounds__(256) void k1_zx(
    const int* __restrict__ tokens, const float* __restrict__ emb,
    const unsigned short* __restrict__ wxt,   // [2][1024][256] bf16
    const float* __restrict__ bf_, const float* __restrict__ bb_,
    unsigned short* __restrict__ zx) {        // [2][512][1024][64] bf16
  int t  = blockIdx.x;
  int ct = blockIdx.y;
  int d  = blockIdx.z;
  int tid = threadIdx.x;
  int w = tid >> 6, lane = tid & 63, q = lane >> 4, l16 = lane & 15;
  int t_src = d ? (511 - t) : t;
  int b_row = w * 16 + l16;
  int tok = tokens[b_row * 512 + t_src];
  const float* embrow = emb + (size_t)tok * 256;
  const unsigned short* wxd = wxt + (size_t)d * 262144;
  const float* bias = d ? bb_ : bf_;

  f32x4 acc[4];
#pragma unroll
  for (int cs = 0; cs < 4; cs++) acc[cs] = {0.f, 0.f, 0.f, 0.f};

#pragma unroll
  for (int kt = 0; kt < 8; kt++) {
    int kbase = kt * 32 + q * 8;
    f32x4 v0 = *(const f32x4*)(embrow + kbase);
    f32x4 v1 = *(const f32x4*)(embrow + kbase + 4);
    short8 afrag;
#pragma unroll
    for (int j = 0; j < 4; j++) {
      afrag[j]     = (short)f2bf(v0[j]);
      afrag[4 + j] = (short)f2bf(v1[j]);
    }
#pragma unroll
    for (int cs = 0; cs < 4; cs++) {
      int gcol = ct * 64 + cs * 16 + l16;
      short8 bfrag = *(const short8*)(wxd + (size_t)gcol * 256 + kbase);
      acc[cs] = __builtin_amdgcn_mfma_f32_16x16x32_bf16(afrag, bfrag, acc[cs], 0, 0, 0);
    }
  }
  // epilogue: +bias, cast bf16, store [t][col][b] (4 consecutive b per lane)
#pragma unroll
  for (int cs = 0; cs < 4; cs++) {
    int gcol = ct * 64 + cs * 16 + l16;
    float bv = bias[gcol];
    ushort4v st;
#pragma unroll
    for (int r = 0; r < 4; r++) st[r] = f2bf(acc[cs][r] + bv);
    size_t idx = ((size_t)(d * 512 + t) * 1024 + gcol) * 64 + (w * 16 + q * 4);
    *(ushort4v*)(zx + idx) = st;
  }
}

// ---------------------------------------------------------------------------
// K2: recurrence. 32 blocks (16/dir), 256 thr. Each wg owns 16 h-dims
// (cols ordered gate-major: local col = gate*16 + j -> all 4 gates land in
// the SAME lane's 4 accumulators -> c-state in registers, no LDS shuffle).
__global__ __launch_bounds__(256) void k2_rnn(
    const unsigned short* __restrict__ zx,    // [2][512][1024][64] bf16
    const unsigned short* __restrict__ wht,   // [2][1024][256] bf16
    unsigned short* __restrict__ hbuf,        // [2][2][64][256] bf16
    int* __restrict__ ctrs) {                 // [2][512]
  int d = blockIdx.x >> 4;
  int s = blockIdx.x & 15;
  int hdbase = s * 16;
  int tid = threadIdx.x;
  int w = tid >> 6, lane = tid & 63, q = lane >> 4, l16 = lane & 15;

  __shared__ unsigned short whtl[64][264];    // 33 KB, padded stride
  const unsigned short* whd = wht + (size_t)d * 262144;
  for (int idx = tid; idx < 2048; idx += 256) {
    int c = idx >> 5, kc = idx & 31;
    int grow = (c >> 4) * 256 + hdbase + (c & 15);    // gate*256 + hd
    *(short8*)(&whtl[c][kc * 8]) = *(const short8*)(whd + (size_t)grow * 256 + kc * 8);
  }
  __syncthreads();

  float cst[4] = {0.f, 0.f, 0.f, 0.f};        // c-state for (b=w*16+q*4+r, j=l16)
  int* myctr = ctrs + d * 512;
  unsigned short* hb = hbuf + (size_t)d * 32768;

  for (int t = 0; t < 512; t++) {
    // prefetch zx for this step (independent of sync)
    ushort4v zv[4];
    size_t zbase = (size_t)(d * 512 + t) * 1024 * 64;
#pragma unroll
    for (int cs = 0; cs < 4; cs++) {
      int gcol = cs * 256 + hdbase + l16;
      zv[cs] = *(const ushort4v*)(zx + zbase + (size_t)gcol * 64 + (w * 16 + q * 4));
    }
    // wait for h_t published by all wgs of this direction
    if (t > 0) {
      if (tid == 0) {
        while (__hip_atomic_load(&myctr[t - 1], __ATOMIC_RELAXED,
                                 __HIP_MEMORY_SCOPE_AGENT) < S_WG) {
          __builtin_amdgcn_s_sleep(1);
        }
        __builtin_amdgcn_fence(__ATOMIC_ACQUIRE, "agent");
      }
      __syncthreads();
    }
    const unsigned short* hr = hb + (t & 1) * 16384;

    f32x4 acc[4];
#pragma unroll
    for (int cs = 0; cs < 4; cs++)
#pragma unroll
      for (int r = 0; r < 4; r++) acc[cs][r] = bf2f(zv[cs][r]);

#pragma unroll
    for (int kt = 0; kt < 8; kt++) {
      int kbase = kt * 32 + q * 8;
      short8 afrag = *(const short8*)(hr + (size_t)(w * 16 + l16) * 256 + kbase);
#pragma unroll
      for (int cs = 0; cs < 4; cs++) {
        short8 bfrag = *(const short8*)(&whtl[cs * 16 + l16][kbase]);
        acc[cs] = __builtin_amdgcn_mfma_f32_16x16x32_bf16(afrag, bfrag, acc[cs], 0, 0, 0);
      }
    }

    unsigned short* hw = hb + ((t + 1) & 1) * 16384;
#pragma unroll
    for (int r = 0; r < 4; r++) {
      float iv = sigf(acc[0][r]);
      float fv = sigf(acc[1][r]);
      float gv = tanhf_(acc[2][r]);
      float ov = sigf(acc[3][r]);
      cst[r] = fv * cst[r] + iv * gv;
      float hv = ov * tanhf_(cst[r]);
      hw[(size_t)(w * 16 + q * 4 + r) * 256 + hdbase + l16] = f2bf(hv);
    }
    __syncthreads();                          // drains all waves' stores
    if (tid == 0) {
      __builtin_amdgcn_fence(__ATOMIC_RELEASE, "agent");
      __hip_atomic_fetch_add(&myctr[t], 1, __ATOMIC_RELAXED, __HIP_MEMORY_SCOPE_AGENT);
    }
  }
}

// ---------------------------------------------------------------------------
// K3: logits + softmax. 64 blocks (one per batch) x 64 threads (one wave).
__global__ __launch_bounds__(64) void k3_out(
    const unsigned short* __restrict__ hbuf,  // final h in buf0 of each dir
    const float* __restrict__ wout, const float* __restrict__ bout,
    float* __restrict__ out) {
  int b = blockIdx.x, tid = threadIdx.x;
  const unsigned short* hf = hbuf;            // dir0 buf0
  const unsigned short* hb = hbuf + 32768;    // dir1 buf0
  float p[10];
#pragma unroll
  for (int l = 0; l < 10; l++) p[l] = 0.f;
  for (int k = tid; k < 512; k += 64) {
    float f = (k < 256) ? bf2f(hf[b * 256 + k]) : bf2f(hb[b * 256 + k - 256]);
    const float* wr = wout + k * 10;
#pragma unroll
    for (int l = 0; l < 10; l++) p[l] += f * wr[l];
  }
#pragma unroll
  for (int off = 32; off; off >>= 1)
#pragma unroll
    for (int l = 0; l < 10; l++) p[l] += __shfl_down(p[l], off);
  if (tid == 0) {
    float lg[10], m = -1e30f;
#pragma unroll
    for (int l = 0; l < 10; l++) { lg[l] = p[l] + bout[l]; m = fmaxf(m, lg[l]); }
    float sum = 0.f;
#pragma unroll
    for (int l = 0; l < 10; l++) { lg[l] = __expf(lg[l] - m); sum += lg[l]; }
    float inv = 1.0f / sum;
#pragma unroll
    for (int l = 0; l < 10; l++) out[b * 10 + l] = lg[l] * inv;
  }
}

// ---------------------------------------------------------------------------
extern "C" void kernel_launch(void* const* d_in, const int* in_sizes, int n_in,
                              void* d_out, int out_size, void* d_ws, size_t ws_size,
                              hipStream_t stream) {
  const int*   tokens = (const int*)d_in[0];
  const float* emb    = (const float*)d_in[1];
  const float* wxf    = (const float*)d_in[2];
  const float* whf    = (const float*)d_in[3];
  const float* bf_    = (const float*)d_in[4];
  const float* wxb    = (const float*)d_in[5];
  const float* whb    = (const float*)d_in[6];
  const float* bb_    = (const float*)d_in[7];
  const float* wout   = (const float*)d_in[8];
  const float* bout   = (const float*)d_in[9];
  float* out = (float*)d_out;

  char* ws = (char*)d_ws;
  unsigned short* zx   = (unsigned short*)(ws + ZX_OFF);
  unsigned short* wxt  = (unsigned short*)(ws + WXT_OFF);
  unsigned short* wht  = (unsigned short*)(ws + WHT_OFF);
  unsigned short* hbuf = (unsigned short*)(ws + HBUF_OFF);
  int*            ctrs = (int*)(ws + CTR_OFF);
  (void)ws_size; (void)in_sizes; (void)n_in; (void)out_size;   // needs WS_NEED bytes

  // zero h0 and step counters (ws is poisoned 0xAA before every timed launch)
  hipMemsetAsync(ws + HBUF_OFF, 0, 131072 + 4096, stream);

  k0_transpose<<<dim3(8, 32, 4), 256, 0, stream>>>(wxf, wxb, whf, whb, wxt, wht);
  k1_zx<<<dim3(512, 16, 2), 256, 0, stream>>>(tokens, emb, wxt, bf_, bb_, zx);
  k2_rnn<<<32, 256, 0, stream>>>(zx, wht, hbuf, ctrs);
  k3_out<<<64, 64, 0, stream>>>(hbuf, wout, bout, out);
}

// Round 2
// 2344.520 us; speedup vs baseline: 1.1711x; 1.1711x over previous
//
#include <hip/hip_runtime.h>
#include <stdint.h>
#include <stddef.h>

// ---------------------------------------------------------------------------
// TextRNN: embed -> BiLSTM(512 steps) -> linear -> softmax   (MI355X gfx950)
//
// K0: transpose/cast Wx,Wh (f32 [256][1024]) -> bf16 [1024][256]  (col-major)
// K1: zx[dir][t][col][b] (bf16) = (emb[tokens] @ Wx + b) via mfma 16x16x32 bf16
// K2: 512-step recurrence; 16 wgs/dir each own 16 h-dims (64 gate cols).
//     R2 change: NO agent fences (they buffer_inv/wbl2 the 4MB L2 every step
//     -> 4.55us/step). All cross-wg traffic (h + counters) uses sc1 (device
//     scope, L1/L2-bypass, served by the coherent memory-side L3). Ordering
//     via s_waitcnt vmcnt(0) only. Per-(dir,wave) counters, no in-loop
//     __syncthreads: wave w consumes only h rows of batches [16w,16w+16),
//     produced exactly by the 16 waves with the same w across the dir's wgs.
// K3: logits = [h_f|h_b] @ W_out + b_out; softmax -> d_out (f32 64x10)
// ---------------------------------------------------------------------------

typedef __attribute__((ext_vector_type(8))) short   short8;
typedef __attribute__((ext_vector_type(4))) float   f32x4;
typedef __attribute__((ext_vector_type(4))) unsigned short ushort4v;
typedef __attribute__((ext_vector_type(4))) unsigned int   uint4v;

// ws byte offsets
#define ZX_OFF    ((size_t)0)                        // 2*512*1024*64 bf16 = 134217728 B
#define WXT_OFF   ((size_t)134217728)                // 2*1024*256 bf16    = 1048576 B
#define WHT_OFF   ((size_t)135266304)                // 2*1024*256 bf16    = 1048576 B
#define HBUF_OFF  ((size_t)136314880)                // 2 dir * 2 buf * 64*256 bf16 = 131072 B
#define CTR_OFF   ((size_t)136445952)                // 2 dir * 4 wave * 512 int = 16384 B
#define WS_NEED   ((size_t)136462336)

__device__ __forceinline__ unsigned short f2bf(float f) {
  unsigned int u = __builtin_bit_cast(unsigned int, f);
  u += 0x7fffu + ((u >> 16) & 1u);            // RNE
  return (unsigned short)(u >> 16);
}
__device__ __forceinline__ float bf2f(unsigned short b) {
  unsigned int u = ((unsigned int)b) << 16;
  return __builtin_bit_cast(float, u);
}
__device__ __forceinline__ float sigf(float x) { return 1.0f / (1.0f + __expf(-x)); }
__device__ __forceinline__ float tanhf_(float x) {
  float t = __expf(-2.0f * fabsf(x));
  float r = (1.0f - t) / (1.0f + t);          // no inf/NaN for any x
  return copysignf(r, x);
}

// ---------------------------------------------------------------------------
// K0: W (f32 [256][1024]) -> Wt (bf16 [1024][256]).  z selects matrix.
__global__ __launch_bounds__(256) void k0_transpose(
    const float* __restrict__ wxf, const float* __restrict__ wxb,
    const float* __restrict__ whf, const float* __restrict__ whb,
    unsigned short* __restrict__ wxt, unsigned short* __restrict__ wht) {
  __shared__ float lds[32][33];
  int mat = blockIdx.z;
  const float* src = (mat == 0) ? wxf : (mat == 1) ? wxb : (mat == 2) ? whf : whb;
  unsigned short* dst = (mat == 0) ? wxt : (mat == 1) ? (wxt + 262144)
                      : (mat == 2) ? wht : (wht + 262144);
  int k0 = blockIdx.x * 32;
  int n0 = blockIdx.y * 32;
  int tx = threadIdx.x & 31, ty = threadIdx.x >> 5;   // ty 0..7
#pragma unroll
  for (int r = 0; r < 4; r++) {
    int k = ty + r * 8;
    lds[k][tx] = src[(size_t)(k0 + k) * 1024 + n0 + tx];
  }
  __syncthreads();
#pragma unroll
  for (int r = 0; r < 4; r++) {
    int n = ty + r * 8;
    dst[(size_t)(n0 + n) * 256 + k0 + tx] = f2bf(lds[tx][n]);
  }
}

// ---------------------------------------------------------------------------
// K1: zx[dir][t][col][b] = emb[tok[b][t_src]] @ Wx + bias   (bf16 out)
// grid (512 t, 16 coltiles, 2 dir), block 256 (4 waves). Tile: 64 b x 64 cols.
__global__ __launch_bounds__(256) void k1_zx(
    const int* __restrict__ tokens, const float* __restrict__ emb,
    const unsigned short* __restrict__ wxt,   // [2][1024][256] bf16
    const float* __restrict__ bf_, const float* __restrict__ bb_,
    unsigned short* __restrict__ zx) {        // [2][512][1024][64] bf16
  int t  = blockIdx.x;
  int ct = blockIdx.y;
  int d  = blockIdx.z;
  int tid = threadIdx.x;
  int w = tid >> 6, lane = tid & 63, q = lane >> 4, l16 = lane & 15;
  int t_src = d ? (511 - t) : t;
  int b_row = w * 16 + l16;
  int tok = tokens[b_row * 512 + t_src];
  const float* embrow = emb + (size_t)tok * 256;
  const unsigned short* wxd = wxt + (size_t)d * 262144;
  const float* bias = d ? bb_ : bf_;

  f32x4 acc[4];
#pragma unroll
  for (int cs = 0; cs < 4; cs++) acc[cs] = {0.f, 0.f, 0.f, 0.f};

#pragma unroll
  for (int kt = 0; kt < 8; kt++) {
    int kbase = kt * 32 + q * 8;
    f32x4 v0 = *(const f32x4*)(embrow + kbase);
    f32x4 v1 = *(const f32x4*)(embrow + kbase + 4);
    short8 afrag;
#pragma unroll
    for (int j = 0; j < 4; j++) {
      afrag[j]     = (short)f2bf(v0[j]);
      afrag[4 + j] = (short)f2bf(v1[j]);
    }
#pragma unroll
    for (int cs = 0; cs < 4; cs++) {
      int gcol = ct * 64 + cs * 16 + l16;
      short8 bfrag = *(const short8*)(wxd + (size_t)gcol * 256 + kbase);
      acc[cs] = __builtin_amdgcn_mfma_f32_16x16x32_bf16(afrag, bfrag, acc[cs], 0, 0, 0);
    }
  }
  // epilogue: +bias, cast bf16, store [t][col][b] (4 consecutive b per lane)
#pragma unroll
  for (int cs = 0; cs < 4; cs++) {
    int gcol = ct * 64 + cs * 16 + l16;
    float bv = bias[gcol];
    ushort4v st;
#pragma unroll
    for (int r = 0; r < 4; r++) st[r] = f2bf(acc[cs][r] + bv);
    size_t idx = ((size_t)(d * 512 + t) * 1024 + gcol) * 64 + (w * 16 + q * 4);
    *(ushort4v*)(zx + idx) = st;
  }
}

// ---------------------------------------------------------------------------
// K2: recurrence. 32 blocks (16/dir), 256 thr. Each wg owns 16 h-dims
// (cols ordered gate-major: local col = gate*16 + j -> all 4 gates land in
// the SAME lane's 4 accumulators -> c-state in registers).
// Cross-wg h exchange: sc1 stores/loads (device scope, no fences), per-wave
// counters ctrs[d][w][t] with target 16.
__global__ __launch_bounds__(256) void k2_rnn(
    const unsigned short* __restrict__ zx,    // [2][512][1024][64] bf16
    const unsigned short* __restrict__ wht,   // [2][1024][256] bf16
    unsigned short* __restrict__ hbuf,        // [2][2][64][256] bf16
    int* __restrict__ ctrs) {                 // [2][4][512]
  int d = blockIdx.x >> 4;
  int s = blockIdx.x & 15;
  int hdbase = s * 16;
  int tid = threadIdx.x;
  int w = tid >> 6, lane = tid & 63, q = lane >> 4, l16 = lane & 15;

  __shared__ unsigned short whtl[64][264];    // 33 KB, padded stride
  const unsigned short* whd = wht + (size_t)d * 262144;
  for (int idx = tid; idx < 2048; idx += 256) {
    int c = idx >> 5, kc = idx & 31;
    int grow = (c >> 4) * 256 + hdbase + (c & 15);    // gate*256 + hd
    *(short8*)(&whtl[c][kc * 8]) = *(const short8*)(whd + (size_t)grow * 256 + kc * 8);
  }
  __syncthreads();

  float cst[4] = {0.f, 0.f, 0.f, 0.f};        // c-state for (b=w*16+q*4+r, j=l16)
  int* ctrw = ctrs + (size_t)(d * 4 + w) * 512;
  unsigned short* hb = hbuf + (size_t)d * 32768;
  int browbase = (w * 16 + l16) * 256;        // this lane's h row (shorts)

  for (int t = 0; t < 512; t++) {
    // prefetch zx for this step (normal cached loads; overlap with the poll)
    ushort4v zv[4];
    size_t zbase = (size_t)(d * 512 + t) * 65536;
#pragma unroll
    for (int cs = 0; cs < 4; cs++) {
      int gcol = cs * 256 + hdbase + l16;
      zv[cs] = *(const ushort4v*)(zx + zbase + (size_t)gcol * 64 + (w * 16 + q * 4));
    }
    // wait for h_t from the 16 producer waves of this (d, w) group
    if (t > 0) {
      while (__hip_atomic_load(&ctrw[t - 1], __ATOMIC_RELAXED,
                               __HIP_MEMORY_SCOPE_AGENT) < 16)
        __builtin_amdgcn_s_sleep(1);
      asm volatile("" ::: "memory");
    }
    const unsigned short* hr = hb + (t & 1) * 16384;
    // 8 x 16B device-coherent (sc1) loads of this lane's h A-fragments,
    // issued together, one vmcnt(0) drain.
    uint4v hfa[8];
    {
      const unsigned short* hptr = hr + browbase + q * 8;
      asm volatile(
          "global_load_dwordx4 %[o0], %[p], off sc1\n\t"
          "global_load_dwordx4 %[o1], %[p], off offset:64 sc1\n\t"
          "global_load_dwordx4 %[o2], %[p], off offset:128 sc1\n\t"
          "global_load_dwordx4 %[o3], %[p], off offset:192 sc1\n\t"
          "global_load_dwordx4 %[o4], %[p], off offset:256 sc1\n\t"
          "global_load_dwordx4 %[o5], %[p], off offset:320 sc1\n\t"
          "global_load_dwordx4 %[o6], %[p], off offset:384 sc1\n\t"
          "global_load_dwordx4 %[o7], %[p], off offset:448 sc1\n\t"
          "s_waitcnt vmcnt(0)"
          : [o0] "=v"(hfa[0]), [o1] "=v"(hfa[1]), [o2] "=v"(hfa[2]),
            [o3] "=v"(hfa[3]), [o4] "=v"(hfa[4]), [o5] "=v"(hfa[5]),
            [o6] "=v"(hfa[6]), [o7] "=v"(hfa[7])
          : [p] "v"(hptr)
          : "memory");
    }

    f32x4 acc[4];
#pragma unroll
    for (int cs = 0; cs < 4; cs++)
#pragma unroll
      for (int r = 0; r < 4; r++) acc[cs][r] = bf2f(zv[cs][r]);

#pragma unroll
    for (int kt = 0; kt < 8; kt++) {
      short8 afrag = __builtin_bit_cast(short8, hfa[kt]);
      int kbase = kt * 32 + q * 8;
#pragma unroll
      for (int cs = 0; cs < 4; cs++) {
        short8 bfrag = *(const short8*)(&whtl[cs * 16 + l16][kbase]);
        acc[cs] = __builtin_amdgcn_mfma_f32_16x16x32_bf16(afrag, bfrag, acc[cs], 0, 0, 0);
      }
    }

    unsigned short* hw = hb + ((t + 1) & 1) * 16384;
#pragma unroll
    for (int r = 0; r < 4; r++) {
      float iv = sigf(acc[0][r]);
      float fv = sigf(acc[1][r]);
      float gv = tanhf_(acc[2][r]);
      float ov = sigf(acc[3][r]);
      cst[r] = fv * cst[r] + iv * gv;
      float hv = ov * tanhf_(cst[r]);
      unsigned int hv16 = f2bf(hv);
      unsigned short* p = hw + (size_t)(w * 16 + q * 4 + r) * 256 + hdbase + l16;
      asm volatile("global_store_short %[p], %[v], off sc1"
                   :: [p] "v"(p), [v] "v"(hv16) : "memory");
    }
    // drain h stores to the coherence point, then publish
    asm volatile("s_waitcnt vmcnt(0)" ::: "memory");
    if (lane == 0)
      __hip_atomic_fetch_add(&ctrw[t], 1, __ATOMIC_RELAXED, __HIP_MEMORY_SCOPE_AGENT);
  }
}

// ---------------------------------------------------------------------------
// K3: logits + softmax. 64 blocks (one per batch) x 64 threads (one wave).
__global__ __launch_bounds__(64) void k3_out(
    const unsigned short* __restrict__ hbuf,  // final h in buf0 of each dir
    const float* __restrict__ wout, const float* __restrict__ bout,
    float* __restrict__ out) {
  int b = blockIdx.x, tid = threadIdx.x;
  const unsigned short* hf = hbuf;            // dir0 buf0
  const unsigned short* hb = hbuf + 32768;    // dir1 buf0
  float p[10];
#pragma unroll
  for (int l = 0; l < 10; l++) p[l] = 0.f;
  for (int k = tid; k < 512; k += 64) {
    float f = (k < 256) ? bf2f(hf[b * 256 + k]) : bf2f(hb[b * 256 + k - 256]);
    const float* wr = wout + k * 10;
#pragma unroll
    for (int l = 0; l < 10; l++) p[l] += f * wr[l];
  }
#pragma unroll
  for (int off = 32; off; off >>= 1)
#pragma unroll
    for (int l = 0; l < 10; l++) p[l] += __shfl_down(p[l], off);
  if (tid == 0) {
    float lg[10], m = -1e30f;
#pragma unroll
    for (int l = 0; l < 10; l++) { lg[l] = p[l] + bout[l]; m = fmaxf(m, lg[l]); }
    float sum = 0.f;
#pragma unroll
    for (int l = 0; l < 10; l++) { lg[l] = __expf(lg[l] - m); sum += lg[l]; }
    float inv = 1.0f / sum;
#pragma unroll
    for (int l = 0; l < 10; l++) out[b * 10 + l] = lg[l] * inv;
  }
}

// ---------------------------------------------------------------------------
extern "C" void kernel_launch(void* const* d_in, const int* in_sizes, int n_in,
                              void* d_out, int out_size, void* d_ws, size_t ws_size,
                              hipStream_t stream) {
  const int*   tokens = (const int*)d_in[0];
  const float* emb    = (const float*)d_in[1];
  const float* wxf    = (const float*)d_in[2];
  const float* whf    = (const float*)d_in[3];
  const float* bf_    = (const float*)d_in[4];
  const float* wxb    = (const float*)d_in[5];
  const float* whb    = (const float*)d_in[6];
  const float* bb_    = (const float*)d_in[7];
  const float* wout   = (const float*)d_in[8];
  const float* bout   = (const float*)d_in[9];
  float* out = (float*)d_out;

  char* ws = (char*)d_ws;
  unsigned short* zx   = (unsigned short*)(ws + ZX_OFF);
  unsigned short* wxt  = (unsigned short*)(ws + WXT_OFF);
  unsigned short* wht  = (unsigned short*)(ws + WHT_OFF);
  unsigned short* hbuf = (unsigned short*)(ws + HBUF_OFF);
  int*            ctrs = (int*)(ws + CTR_OFF);
  (void)ws_size; (void)in_sizes; (void)n_in; (void)out_size;   // needs WS_NEED bytes

  // zero h0 and step counters (ws is poisoned 0xAA before every timed launch)
  hipMemsetAsync(ws + HBUF_OFF, 0, 131072 + 16384, stream);

  k0_transpose<<<dim3(8, 32, 4), 256, 0, stream>>>(wxf, wxb, whf, whb, wxt, wht);
  k1_zx<<<dim3(512, 16, 2), 256, 0, stream>>>(tokens, emb, wxt, bf_, bb_, zx);
  k2_rnn<<<32, 256, 0, stream>>>(zx, wht, hbuf, ctrs);
  k3_out<<<64, 64, 0, stream>>>(hbuf, wout, bout, out);
}

// Round 3
// 2264.537 us; speedup vs baseline: 1.2125x; 1.0353x over previous
//
#include <hip/hip_runtime.h>
#include <stdint.h>
#include <stddef.h>

// ---------------------------------------------------------------------------
// TextRNN: embed -> BiLSTM(512 steps) -> linear -> softmax   (MI355X gfx950)
//
// K0: transpose/cast Wx,Wh (f32 [256][1024]) -> bf16 [1024][256]  (col-major)
// K1: zx[dir][t][col][b] (bf16) = (emb[tokens] @ Wx + b) via mfma 16x16x32 bf16
// K2: 512-step recurrence; 16 wgs/dir each own 16 h-dims (64 gate cols).
//     R3 change: counter sync removed. h is exchanged as u32 words
//     (step_tag<<16 | bf16) via sc1 (device-scope, coherent at L3). The
//     consumer's poll IS the data load: re-load A-fragments until all tags
//     match t (wave-wide __all vote). Dword stores are single-copy atomic ->
//     no per-word tearing; double-buffering makes overwrite provably safe.
//     Critical path/step = own store drain (|| others' propagation) + one
//     poll-load RT + compute.  (R2 had 4 serialized L3 RTs: drain, atomic,
//     counter-poll, h-load -> 3.7us/step.)
// K3: logits = [h_f|h_b] @ W_out + b_out; softmax -> d_out (f32 64x10)
// ---------------------------------------------------------------------------

typedef __attribute__((ext_vector_type(8))) short   short8;
typedef __attribute__((ext_vector_type(4))) float   f32x4;
typedef __attribute__((ext_vector_type(4))) unsigned short ushort4v;
typedef __attribute__((ext_vector_type(4))) unsigned int   uint4v;

// ws byte offsets
#define ZX_OFF    ((size_t)0)                        // 2*512*1024*64 bf16 = 134217728 B
#define WXT_OFF   ((size_t)134217728)                // 2*1024*256 bf16    = 1048576 B
#define WHT_OFF   ((size_t)135266304)                // 2*1024*256 bf16    = 1048576 B
#define HBUF_OFF  ((size_t)136314880)                // 2 dir * 2 buf * 64*256 u32 = 262144 B
#define WS_NEED   ((size_t)136577024)

__device__ __forceinline__ unsigned short f2bf(float f) {
  unsigned int u = __builtin_bit_cast(unsigned int, f);
  u += 0x7fffu + ((u >> 16) & 1u);            // RNE
  return (unsigned short)(u >> 16);
}
__device__ __forceinline__ float bf2f(unsigned short b) {
  unsigned int u = ((unsigned int)b) << 16;
  return __builtin_bit_cast(float, u);
}
__device__ __forceinline__ float sigf(float x) { return 1.0f / (1.0f + __expf(-x)); }
__device__ __forceinline__ float tanhf_(float x) {
  float t = __expf(-2.0f * fabsf(x));
  float r = (1.0f - t) / (1.0f + t);          // no inf/NaN for any x
  return copysignf(r, x);
}

// ---------------------------------------------------------------------------
// K0: W (f32 [256][1024]) -> Wt (bf16 [1024][256]).  z selects matrix.
__global__ __launch_bounds__(256) void k0_transpose(
    const float* __restrict__ wxf, const float* __restrict__ wxb,
    const float* __restrict__ whf, const float* __restrict__ whb,
    unsigned short* __restrict__ wxt, unsigned short* __restrict__ wht) {
  __shared__ float lds[32][33];
  int mat = blockIdx.z;
  const float* src = (mat == 0) ? wxf : (mat == 1) ? wxb : (mat == 2) ? whf : whb;
  unsigned short* dst = (mat == 0) ? wxt : (mat == 1) ? (wxt + 262144)
                      : (mat == 2) ? wht : (wht + 262144);
  int k0 = blockIdx.x * 32;
  int n0 = blockIdx.y * 32;
  int tx = threadIdx.x & 31, ty = threadIdx.x >> 5;   // ty 0..7
#pragma unroll
  for (int r = 0; r < 4; r++) {
    int k = ty + r * 8;
    lds[k][tx] = src[(size_t)(k0 + k) * 1024 + n0 + tx];
  }
  __syncthreads();
#pragma unroll
  for (int r = 0; r < 4; r++) {
    int n = ty + r * 8;
    dst[(size_t)(n0 + n) * 256 + k0 + tx] = f2bf(lds[tx][n]);
  }
}

// ---------------------------------------------------------------------------
// K1: zx[dir][t][col][b] = emb[tok[b][t_src]] @ Wx + bias   (bf16 out)
// grid (512 t, 16 coltiles, 2 dir), block 256 (4 waves). Tile: 64 b x 64 cols.
__global__ __launch_bounds__(256) void k1_zx(
    const int* __restrict__ tokens, const float* __restrict__ emb,
    const unsigned short* __restrict__ wxt,   // [2][1024][256] bf16
    const float* __restrict__ bf_, const float* __restrict__ bb_,
    unsigned short* __restrict__ zx) {        // [2][512][1024][64] bf16
  int t  = blockIdx.x;
  int ct = blockIdx.y;
  int d  = blockIdx.z;
  int tid = threadIdx.x;
  int w = tid >> 6, lane = tid & 63, q = lane >> 4, l16 = lane & 15;
  int t_src = d ? (511 - t) : t;
  int b_row = w * 16 + l16;
  int tok = tokens[b_row * 512 + t_src];
  const float* embrow = emb + (size_t)tok * 256;
  const unsigned short* wxd = wxt + (size_t)d * 262144;
  const float* bias = d ? bb_ : bf_;

  f32x4 acc[4];
#pragma unroll
  for (int cs = 0; cs < 4; cs++) acc[cs] = {0.f, 0.f, 0.f, 0.f};

#pragma unroll
  for (int kt = 0; kt < 8; kt++) {
    int kbase = kt * 32 + q * 8;
    f32x4 v0 = *(const f32x4*)(embrow + kbase);
    f32x4 v1 = *(const f32x4*)(embrow + kbase + 4);
    short8 afrag;
#pragma unroll
    for (int j = 0; j < 4; j++) {
      afrag[j]     = (short)f2bf(v0[j]);
      afrag[4 + j] = (short)f2bf(v1[j]);
    }
#pragma unroll
    for (int cs = 0; cs < 4; cs++) {
      int gcol = ct * 64 + cs * 16 + l16;
      short8 bfrag = *(const short8*)(wxd + (size_t)gcol * 256 + kbase);
      acc[cs] = __builtin_amdgcn_mfma_f32_16x16x32_bf16(afrag, bfrag, acc[cs], 0, 0, 0);
    }
  }
  // epilogue: +bias, cast bf16, store [t][col][b] (4 consecutive b per lane)
#pragma unroll
  for (int cs = 0; cs < 4; cs++) {
    int gcol = ct * 64 + cs * 16 + l16;
    float bv = bias[gcol];
    ushort4v st;
#pragma unroll
    for (int r = 0; r < 4; r++) st[r] = f2bf(acc[cs][r] + bv);
    size_t idx = ((size_t)(d * 512 + t) * 1024 + gcol) * 64 + (w * 16 + q * 4);
    *(ushort4v*)(zx + idx) = st;
  }
}

// ---------------------------------------------------------------------------
// K2: recurrence. 32 blocks (16/dir), 256 thr. Each wg owns 16 h-dims
// (cols ordered gate-major: local col = gate*16 + j -> all 4 gates land in
// the SAME lane's 4 accumulators -> c-state in registers).
// h exchange: tagged u32 words ((t<<16)|bf16) via sc1; poll-the-data sync.
__global__ __launch_bounds__(256) void k2_rnn(
    const unsigned short* __restrict__ zx,    // [2][512][1024][64] bf16
    const unsigned short* __restrict__ wht,   // [2][1024][256] bf16
    unsigned int* __restrict__ hbufw) {       // [2][2][64][256] u32 tagged
  int d = blockIdx.x >> 4;
  int s = blockIdx.x & 15;
  int hdbase = s * 16;
  int tid = threadIdx.x;
  int w = tid >> 6, lane = tid & 63, q = lane >> 4, l16 = lane & 15;

  __shared__ unsigned short whtl[64][264];    // 33 KB, padded stride
  const unsigned short* whd = wht + (size_t)d * 262144;
  for (int idx = tid; idx < 2048; idx += 256) {
    int c = idx >> 5, kc = idx & 31;
    int grow = (c >> 4) * 256 + hdbase + (c & 15);    // gate*256 + hd
    *(short8*)(&whtl[c][kc * 8]) = *(const short8*)(whd + (size_t)grow * 256 + kc * 8);
  }
  __syncthreads();

  float cst[4] = {0.f, 0.f, 0.f, 0.f};        // c-state for (b=w*16+q*4+r, j=l16)
  unsigned int* hb = hbufw + (size_t)d * 32768;           // words
  int rowoff = (w * 16 + l16) * 256 + q * 8;              // consumer base (words)
  int srow   = (w * 16 + q * 4) * 256 + hdbase + l16;     // producer base (words)

  for (int t = 0; t < 512; t++) {
    // prefetch zx for this step (normal cached loads; overlap with the poll)
    ushort4v zv[4];
    size_t zbase = (size_t)(d * 512 + t) * 65536;
#pragma unroll
    for (int cs = 0; cs < 4; cs++) {
      int gcol = cs * 256 + hdbase + l16;
      zv[cs] = *(const ushort4v*)(zx + zbase + (size_t)gcol * 64 + (w * 16 + q * 4));
    }

    // poll-load this lane's h A-fragments (tagged words) until tags == t.
    // Layout per lane: 8 chunks (kt) of 8 words at word-stride 32
    // (byte offsets kt*128 + {0,16}).
    const unsigned int* hp = hb + (t & 1) * 16384 + rowoff;
    unsigned int tg = (unsigned int)t << 16;
    uint4v hA[8], hB[8];
    while (true) {
      asm volatile(
          "global_load_dwordx4 %[a0], %[p], off sc1\n\t"
          "global_load_dwordx4 %[b0], %[p], off offset:16 sc1\n\t"
          "global_load_dwordx4 %[a1], %[p], off offset:128 sc1\n\t"
          "global_load_dwordx4 %[b1], %[p], off offset:144 sc1\n\t"
          "global_load_dwordx4 %[a2], %[p], off offset:256 sc1\n\t"
          "global_load_dwordx4 %[b2], %[p], off offset:272 sc1\n\t"
          "global_load_dwordx4 %[a3], %[p], off offset:384 sc1\n\t"
          "global_load_dwordx4 %[b3], %[p], off offset:400 sc1\n\t"
          "global_load_dwordx4 %[a4], %[p], off offset:512 sc1\n\t"
          "global_load_dwordx4 %[b4], %[p], off offset:528 sc1\n\t"
          "global_load_dwordx4 %[a5], %[p], off offset:640 sc1\n\t"
          "global_load_dwordx4 %[b5], %[p], off offset:656 sc1\n\t"
          "global_load_dwordx4 %[a6], %[p], off offset:768 sc1\n\t"
          "global_load_dwordx4 %[b6], %[p], off offset:784 sc1\n\t"
          "global_load_dwordx4 %[a7], %[p], off offset:896 sc1\n\t"
          "global_load_dwordx4 %[b7], %[p], off offset:912 sc1\n\t"
          "s_waitcnt vmcnt(0)"
          : [a0] "=v"(hA[0]), [b0] "=v"(hB[0]), [a1] "=v"(hA[1]), [b1] "=v"(hB[1]),
            [a2] "=v"(hA[2]), [b2] "=v"(hB[2]), [a3] "=v"(hA[3]), [b3] "=v"(hB[3]),
            [a4] "=v"(hA[4]), [b4] "=v"(hB[4]), [a5] "=v"(hA[5]), [b5] "=v"(hB[5]),
            [a6] "=v"(hA[6]), [b6] "=v"(hB[6]), [a7] "=v"(hA[7]), [b7] "=v"(hB[7])
          : [p] "v"(hp)
          : "memory");
      // one tag per 16B chunk (chunk = snapshot of one coalesced producer store)
      unsigned int bad =
          (hA[0][0] ^ tg) | (hB[0][0] ^ tg) | (hA[1][0] ^ tg) | (hB[1][0] ^ tg) |
          (hA[2][0] ^ tg) | (hB[2][0] ^ tg) | (hA[3][0] ^ tg) | (hB[3][0] ^ tg) |
          (hA[4][0] ^ tg) | (hB[4][0] ^ tg) | (hA[5][0] ^ tg) | (hB[5][0] ^ tg) |
          (hA[6][0] ^ tg) | (hB[6][0] ^ tg) | (hA[7][0] ^ tg) | (hB[7][0] ^ tg);
      if (__all((bad & 0xffff0000u) == 0)) break;
    }

    f32x4 acc[4];
#pragma unroll
    for (int cs = 0; cs < 4; cs++)
#pragma unroll
      for (int r = 0; r < 4; r++) acc[cs][r] = bf2f(zv[cs][r]);

#pragma unroll
    for (int kt = 0; kt < 8; kt++) {
      // pack 8 tagged words -> 8 bf16 (v_perm_b32, low halves)
      uint4v pk;
      pk[0] = __builtin_amdgcn_perm(hA[kt][1], hA[kt][0], 0x05040100u);
      pk[1] = __builtin_amdgcn_perm(hA[kt][3], hA[kt][2], 0x05040100u);
      pk[2] = __builtin_amdgcn_perm(hB[kt][1], hB[kt][0], 0x05040100u);
      pk[3] = __builtin_amdgcn_perm(hB[kt][3], hB[kt][2], 0x05040100u);
      short8 afrag = __builtin_bit_cast(short8, pk);
      int kbase = kt * 32 + q * 8;
#pragma unroll
      for (int cs = 0; cs < 4; cs++) {
        short8 bfrag = *(const short8*)(&whtl[cs * 16 + l16][kbase]);
        acc[cs] = __builtin_amdgcn_mfma_f32_16x16x32_bf16(afrag, bfrag, acc[cs], 0, 0, 0);
      }
    }

    unsigned int* hwn = hb + ((t + 1) & 1) * 16384 + srow;
    unsigned int wtag = ((unsigned int)(t + 1)) << 16;
    unsigned int sw[4];
#pragma unroll
    for (int r = 0; r < 4; r++) {
      float iv = sigf(acc[0][r]);
      float fv = sigf(acc[1][r]);
      float gv = tanhf_(acc[2][r]);
      float ov = sigf(acc[3][r]);
      cst[r] = fv * cst[r] + iv * gv;
      float hv = ov * tanhf_(cst[r]);
      sw[r] = wtag | (unsigned int)f2bf(hv);
    }
    // tagged h stores (rows r at word-stride 256 = 1024 B) + drain.
    // The drain overlaps other producers' propagation (lockstep-neutral).
    asm volatile(
        "global_store_dword %[p], %[v0], off sc1\n\t"
        "global_store_dword %[p], %[v1], off offset:1024 sc1\n\t"
        "global_store_dword %[p], %[v2], off offset:2048 sc1\n\t"
        "global_store_dword %[p], %[v3], off offset:3072 sc1\n\t"
        "s_waitcnt vmcnt(0)"
        :: [p] "v"(hwn), [v0] "v"(sw[0]), [v1] "v"(sw[1]),
           [v2] "v"(sw[2]), [v3] "v"(sw[3])
        : "memory");
  }
}

// ---------------------------------------------------------------------------
// K3: logits + softmax. 64 blocks (one per batch) x 64 threads (one wave).
// Final h_512 sits in buf0 of each dir (tagged words; low16 = bf16 value).
__global__ __launch_bounds__(64) void k3_out(
    const unsigned int* __restrict__ hbufw,
    const float* __restrict__ wout, const float* __restrict__ bout,
    float* __restrict__ out) {
  int b = blockIdx.x, tid = threadIdx.x;
  const unsigned int* hf  = hbufw;            // dir0 buf0
  const unsigned int* hbk = hbufw + 32768;    // dir1 buf0
  float p[10];
#pragma unroll
  for (int l = 0; l < 10; l++) p[l] = 0.f;
  for (int k = tid; k < 512; k += 64) {
    unsigned int wd = (k < 256) ? hf[b * 256 + k] : hbk[b * 256 + k - 256];
    float f = bf2f((unsigned short)(wd & 0xffffu));
    const float* wr = wout + k * 10;
#pragma unroll
    for (int l = 0; l < 10; l++) p[l] += f * wr[l];
  }
#pragma unroll
  for (int off = 32; off; off >>= 1)
#pragma unroll
    for (int l = 0; l < 10; l++) p[l] += __shfl_down(p[l], off);
  if (tid == 0) {
    float lg[10], m = -1e30f;
#pragma unroll
    for (int l = 0; l < 10; l++) { lg[l] = p[l] + bout[l]; m = fmaxf(m, lg[l]); }
    float sum = 0.f;
#pragma unroll
    for (int l = 0; l < 10; l++) { lg[l] = __expf(lg[l] - m); sum += lg[l]; }
    float inv = 1.0f / sum;
#pragma unroll
    for (int l = 0; l < 10; l++) out[b * 10 + l] = lg[l] * inv;
  }
}

// ---------------------------------------------------------------------------
extern "C" void kernel_launch(void* const* d_in, const int* in_sizes, int n_in,
                              void* d_out, int out_size, void* d_ws, size_t ws_size,
                              hipStream_t stream) {
  const int*   tokens = (const int*)d_in[0];
  const float* emb    = (const float*)d_in[1];
  const float* wxf    = (const float*)d_in[2];
  const float* whf    = (const float*)d_in[3];
  const float* bf_    = (const float*)d_in[4];
  const float* wxb    = (const float*)d_in[5];
  const float* whb    = (const float*)d_in[6];
  const float* bb_    = (const float*)d_in[7];
  const float* wout   = (const float*)d_in[8];
  const float* bout   = (const float*)d_in[9];
  float* out = (float*)d_out;

  char* ws = (char*)d_ws;
  unsigned short* zx    = (unsigned short*)(ws + ZX_OFF);
  unsigned short* wxt   = (unsigned short*)(ws + WXT_OFF);
  unsigned short* wht   = (unsigned short*)(ws + WHT_OFF);
  unsigned int*   hbufw = (unsigned int*)(ws + HBUF_OFF);
  (void)ws_size; (void)in_sizes; (void)n_in; (void)out_size;   // needs WS_NEED bytes

  // zero h0 (tag 0 == step 0); poison 0xAAAA never matches a tag (<= 512)
  hipMemsetAsync(ws + HBUF_OFF, 0, 262144, stream);

  k0_transpose<<<dim3(8, 32, 4), 256, 0, stream>>>(wxf, wxb, whf, whb, wxt, wht);
  k1_zx<<<dim3(512, 16, 2), 256, 0, stream>>>(tokens, emb, wxt, bf_, bb_, zx);
  k2_rnn<<<32, 256, 0, stream>>>(zx, wht, hbufw);
  k3_out<<<64, 64, 0, stream>>>(hbufw, wout, bout, out);
}